// Round 6
// baseline (20.652 us; speedup 1.0000x reference)
//
#include <hip/hip_runtime.h>

// DiffAugment fused: flip -> brightness -> contrast -> translation -> cutout
// B=64, C=3, H=W=256, fp32.
// One wave per (b,h) row, all 3 channels. b is blockIdx-derived -> params
// scalarize. NO LDS: the translation w-gather (shift by tw, |tw|<=16, rare
// mod-255 wrap) is served by unaligned contiguous float4 global loads for
// wrap-free lanes (>=59/64) and a scalar fixup for the boundary lanes.
// Brightness+contrast+cutout fold to one FMA per pixel. NT stores (output
// is never re-read).

#define Bc 64
#define Cc 3
#define Hc 256
#define Wc 256
#define CH (Hc * Wc)

typedef float f32x4  __attribute__((ext_vector_type(4)));
typedef float f32x4u __attribute__((ext_vector_type(4), aligned(4)));  // unaligned-ok

__device__ __forceinline__ void store_nt(float* p, f32x4 v) {
    __builtin_nontemporal_store(v, reinterpret_cast<f32x4*>(p));
}

__global__ __launch_bounds__(256) void diffaug_kernel(
    const float* __restrict__ x,
    const float* __restrict__ p_,
    const float* __restrict__ flip_u,
    const float* __restrict__ bright_n,
    const float* __restrict__ bright_u,
    const float* __restrict__ contrast_n,
    const float* __restrict__ contrast_u,
    const int*   __restrict__ trans_h,
    const int*   __restrict__ trans_w,
    const float* __restrict__ trans_u,
    const int*   __restrict__ cut_ox,
    const int*   __restrict__ cut_oy,
    const float* __restrict__ cut_u,
    float* __restrict__ out)
{
    const int lane = threadIdx.x & 63;
    const int wave = threadIdx.x >> 6;
    const int b    = blockIdx.x >> 6;                  // block-uniform (SGPR)
    const int h    = ((blockIdx.x & 63) << 2) | wave;  // wave-uniform
    const int w0   = lane << 2;

    // Per-image params — uniform address -> scalar loads.
    const float p    = p_[0];
    const bool  flip = flip_u[b] < 0.5f * p;
    const float badd = (bright_u[b]   < p) ? bright_n[b]   * 0.2f : 0.0f;
    const float cmul = (contrast_u[b] < p) ? exp2f(contrast_n[b] * 0.5f) : 1.0f;
    const bool  do_t   = trans_u[b] < p;
    const bool  do_cut = cut_u[b]   < p;
    const int   ox = cut_ox[b], oy = cut_oy[b];

    // Fold brightness/contrast/cutout into one fma per pixel: o = v*scl+off.
    const bool hcut = do_cut && (h >= ox - 64) && (h <= ox + 63);
    float scl[4], off[4];
    #pragma unroll
    for (int j = 0; j < 4; ++j) {
        const int w = w0 + j;
        const bool cut = hcut && (w >= oy - 64) && (w <= oy + 63);
        scl[j] = cut ? 0.f : cmul;
        off[j] = cut ? 0.f : badd * cmul;
    }

    const size_t rowbase = (size_t)(b * Cc) * CH + (size_t)h * Wc + w0;

    if (!do_t) {
        if (!flip) {
            // ---- path 1: pure elementwise ----
            #pragma unroll
            for (int c = 0; c < Cc; ++c) {
                f32x4 v = *reinterpret_cast<const f32x4*>(&x[rowbase + c * CH]);
                f32x4 o;
                o[0] = v[0] * scl[0] + off[0];
                o[1] = v[1] * scl[1] + off[1];
                o[2] = v[2] * scl[2] + off[2];
                o[3] = v[3] * scl[3] + off[3];
                store_nt(&out[rowbase + c * CH], o);
            }
        } else {
            // ---- path 2: flip-only: reversed aligned float4 window ----
            const size_t rb = (size_t)(b * Cc) * CH + (size_t)h * Wc + (252 - w0);
            #pragma unroll
            for (int c = 0; c < Cc; ++c) {
                f32x4 v = *reinterpret_cast<const f32x4*>(&x[rb + c * CH]);
                f32x4 o;
                o[0] = v[3] * scl[0] + off[0];
                o[1] = v[2] * scl[1] + off[1];
                o[2] = v[1] * scl[2] + off[2];
                o[3] = v[0] * scl[3] + off[3];
                store_nt(&out[rowbase + c * CH], o);
            }
        }
        return;
    }

    // ---- path 3: translation (flip folded into source index), no LDS ----
    // torch quirks: H padded by 1 each side (pad rows zero); w wraps
    // python-mod (W-1), so source index ws = pymod(w+tw, 255), then
    // flip maps to 255-ws. |tw| <= 16.
    const int th = trans_h[b], tw = trans_w[b];
    int g = h + th + 1;
    g = min(max(g, 0), Hc + 1);

    if ((g == 0) | (g == Hc + 1)) {
        const f32x4 z = {0.f, 0.f, 0.f, 0.f};
        #pragma unroll
        for (int c = 0; c < Cc; ++c)
            store_nt(&out[rowbase + c * CH], z);
        return;
    }

    const int hs = g - 1;                              // in [0, 255]
    const float* __restrict__ rowp = &x[(size_t)(b * Cc) * CH + (size_t)hs * Wc];

    // Wrap-free lanes: all 4 source indices are w0+j+tw with no mod needed.
    const bool wrapfree = (w0 + tw >= 0) & (w0 + 3 + tw <= Wc - 2);

    f32x4 v0, v1, v2;
    if (wrapfree) {
        // Contiguous (possibly unaligned) 16B window; reversed if flip.
        const int src = flip ? (252 - tw - w0) : (w0 + tw);   // in [0, 252]
        f32x4 t0 = *reinterpret_cast<const f32x4u*>(&rowp[src]);
        f32x4 t1 = *reinterpret_cast<const f32x4u*>(&rowp[CH + src]);
        f32x4 t2 = *reinterpret_cast<const f32x4u*>(&rowp[2 * CH + src]);
        if (flip) {
            v0 = f32x4{t0[3], t0[2], t0[1], t0[0]};
            v1 = f32x4{t1[3], t1[2], t1[1], t1[0]};
            v2 = f32x4{t2[3], t2[2], t2[1], t2[0]};
        } else {
            v0 = t0; v1 = t1; v2 = t2;
        }
    } else {
        // Boundary lanes (<=5 per wave): scalar gather with python-mod wrap.
        #pragma unroll
        for (int j = 0; j < 4; ++j) {
            int ws = w0 + j + tw;                    // in [-16, 270]
            if (ws < 0)            ws += (Wc - 1);
            else if (ws >= Wc - 1) ws -= (Wc - 1);
            const int idx = flip ? (Wc - 1 - ws) : ws;
            v0[j] = rowp[idx];
            v1[j] = rowp[CH + idx];
            v2[j] = rowp[2 * CH + idx];
        }
    }

    #pragma unroll
    for (int c = 0; c < Cc; ++c) {
        const f32x4& v = (c == 0) ? v0 : (c == 1) ? v1 : v2;
        f32x4 o;
        o[0] = v[0] * scl[0] + off[0];
        o[1] = v[1] * scl[1] + off[1];
        o[2] = v[2] * scl[2] + off[2];
        o[3] = v[3] * scl[3] + off[3];
        store_nt(&out[rowbase + c * CH], o);
    }
}

extern "C" void kernel_launch(void* const* d_in, const int* in_sizes, int n_in,
                              void* d_out, int out_size, void* d_ws, size_t ws_size,
                              hipStream_t stream) {
    const float* x          = (const float*)d_in[0];
    const float* p          = (const float*)d_in[1];
    const float* flip_u     = (const float*)d_in[2];
    const float* bright_n   = (const float*)d_in[3];
    const float* bright_u   = (const float*)d_in[4];
    const float* contrast_n = (const float*)d_in[5];
    const float* contrast_u = (const float*)d_in[6];
    const int*   trans_h    = (const int*)d_in[7];
    const int*   trans_w    = (const int*)d_in[8];
    const float* trans_u    = (const float*)d_in[9];
    const int*   cut_ox     = (const int*)d_in[10];
    const int*   cut_oy     = (const int*)d_in[11];
    const float* cut_u      = (const float*)d_in[12];
    float*       out        = (float*)d_out;

    dim3 grid(Bc * Hc / 4);    // 4096 blocks: (b, h-quad); wave = one (b,h) row
    dim3 block(256);
    diffaug_kernel<<<grid, block, 0, stream>>>(
        x, p, flip_u, bright_n, bright_u, contrast_n, contrast_u,
        trans_h, trans_w, trans_u, cut_ox, cut_oy, cut_u, out);
}

// Round 9
// 20.585 us; speedup vs baseline: 1.0032x; 1.0032x over previous
//
#include <hip/hip_runtime.h>

// DiffAugment fused: flip -> brightness -> contrast -> translation -> cutout
// B=64, C=3, H=W=256, fp32.
// One wave per (b, h-pair): 2 h-rows x 3 channels = 6 float4 loads + 6 NT
// stores in flight per thread. b is blockIdx-derived -> params scalarize.
// No LDS. Translation w-gather = unaligned contiguous float4 windows
// (wrap-free lanes) + scalar pymod fixup for boundary lanes.
// Epilogue per pixel: o = cut ? 0 : v*cmul + off_row, where off_row = 0 for
// translated-in pad rows (brightness is applied BEFORE padding in the ref —
// pad rows must be exactly zero; this was round-8's bug).

#define Bc 64
#define Cc 3
#define Hc 256
#define Wc 256
#define CH (Hc * Wc)

typedef float f32x4  __attribute__((ext_vector_type(4)));
typedef float f32x4u __attribute__((ext_vector_type(4), aligned(4)));

__device__ __forceinline__ void store_nt(float* p, f32x4 v) {
    __builtin_nontemporal_store(v, reinterpret_cast<f32x4*>(p));
}
__device__ __forceinline__ f32x4 rev4(f32x4 t) { return f32x4{t[3], t[2], t[1], t[0]}; }

__global__ __launch_bounds__(256) void diffaug_kernel(
    const float* __restrict__ x,
    const float* __restrict__ p_,
    const float* __restrict__ flip_u,
    const float* __restrict__ bright_n,
    const float* __restrict__ bright_u,
    const float* __restrict__ contrast_n,
    const float* __restrict__ contrast_u,
    const int*   __restrict__ trans_h,
    const int*   __restrict__ trans_w,
    const float* __restrict__ trans_u,
    const int*   __restrict__ cut_ox,
    const int*   __restrict__ cut_oy,
    const float* __restrict__ cut_u,
    float* __restrict__ out)
{
    const int lane = threadIdx.x & 63;
    const int wave = threadIdx.x >> 6;
    const int b    = blockIdx.x >> 5;                         // SGPR-uniform
    const int h0   = ((blockIdx.x & 31) << 3) | (wave << 1);  // even, wave-uniform
    const int w0   = lane << 2;

    // Per-image params — uniform address -> scalar loads.
    const float p    = p_[0];
    const bool  flip = flip_u[b] < 0.5f * p;
    const float badd = (bright_u[b]   < p) ? bright_n[b]   * 0.2f : 0.0f;
    const float cmul = (contrast_u[b] < p) ? exp2f(contrast_n[b] * 0.5f) : 1.0f;
    const bool  do_t   = trans_u[b] < p;
    const bool  do_cut = cut_u[b]   < p;
    const int   ox = cut_ox[b], oy = cut_oy[b];
    const float offv = badd * cmul;

    // Cutout masks: w-part per lane-pixel, h-part per row.
    bool wcut[4];
    #pragma unroll
    for (int j = 0; j < 4; ++j) {
        const int w = w0 + j;
        wcut[j] = do_cut & (w >= oy - 64) & (w <= oy + 63);
    }
    const bool hcut0 = (h0     >= ox - 64) & (h0     <= ox + 63);
    const bool hcut1 = (h0 + 1 >= ox - 64) & (h0 + 1 <= ox + 63);

    const size_t plane = (size_t)(b * Cc) * CH;
    const size_t dst0  = plane + (size_t)h0 * Wc + w0;   // row h0, +Wc for h0+1

    f32x4 va0, va1, va2, vb0, vb1, vb2;    // [row a/b][channel]
    float offa = offv, offb = offv;        // per-row additive term

    if (!do_t) {
        const size_t sa = flip ? (plane + (size_t)h0 * Wc + (252 - w0)) : dst0;
        va0 = *reinterpret_cast<const f32x4*>(&x[sa]);
        va1 = *reinterpret_cast<const f32x4*>(&x[sa + CH]);
        va2 = *reinterpret_cast<const f32x4*>(&x[sa + 2 * CH]);
        vb0 = *reinterpret_cast<const f32x4*>(&x[sa + Wc]);
        vb1 = *reinterpret_cast<const f32x4*>(&x[sa + Wc + CH]);
        vb2 = *reinterpret_cast<const f32x4*>(&x[sa + Wc + 2 * CH]);
        if (flip) {
            va0 = rev4(va0); va1 = rev4(va1); va2 = rev4(va2);
            vb0 = rev4(vb0); vb1 = rev4(vb1); vb2 = rev4(vb2);
        }
    } else {
        // Translation (torch quirks: H padded by 1 each side, pad rows zero;
        // w wraps python-mod (W-1); flip folds into source index 255-ws).
        // Brightness/contrast were applied BEFORE padding -> pad rows are
        // exactly zero: zero the row AND its additive offset.
        const int th = trans_h[b], tw = trans_w[b];
        int g0 = min(max(h0     + th + 1, 0), Hc + 1);
        int g1 = min(max(h0 + 1 + th + 1, 0), Hc + 1);
        const bool z0 = (g0 == 0) | (g0 == Hc + 1);
        const bool z1 = (g1 == 0) | (g1 == Hc + 1);
        const int  hs0 = min(max(g0 - 1, 0), Hc - 1);
        const int  hs1 = min(max(g1 - 1, 0), Hc - 1);
        const float* rowa = &x[plane + (size_t)hs0 * Wc];
        const float* rowb = &x[plane + (size_t)hs1 * Wc];

        const bool wrapfree = (w0 + tw >= 0) & (w0 + 3 + tw <= Wc - 2);
        if (wrapfree) {
            const int src = flip ? (252 - tw - w0) : (w0 + tw);  // in [0,252]
            va0 = *reinterpret_cast<const f32x4u*>(&rowa[src]);
            va1 = *reinterpret_cast<const f32x4u*>(&rowa[CH + src]);
            va2 = *reinterpret_cast<const f32x4u*>(&rowa[2 * CH + src]);
            vb0 = *reinterpret_cast<const f32x4u*>(&rowb[src]);
            vb1 = *reinterpret_cast<const f32x4u*>(&rowb[CH + src]);
            vb2 = *reinterpret_cast<const f32x4u*>(&rowb[2 * CH + src]);
            if (flip) {
                va0 = rev4(va0); va1 = rev4(va1); va2 = rev4(va2);
                vb0 = rev4(vb0); vb1 = rev4(vb1); vb2 = rev4(vb2);
            }
        } else {
            // Boundary lanes (<=5/64): scalar gather with python-mod wrap.
            #pragma unroll
            for (int j = 0; j < 4; ++j) {
                int ws = w0 + j + tw;                    // in [-16, 270]
                if (ws < 0)            ws += (Wc - 1);
                else if (ws >= Wc - 1) ws -= (Wc - 1);
                const int idx = flip ? (Wc - 1 - ws) : ws;
                va0[j] = rowa[idx];  va1[j] = rowa[CH + idx];  va2[j] = rowa[2 * CH + idx];
                vb0[j] = rowb[idx];  vb1[j] = rowb[CH + idx];  vb2[j] = rowb[2 * CH + idx];
            }
        }
        if (z0) { va0 = va1 = va2 = f32x4{0.f, 0.f, 0.f, 0.f}; offa = 0.f; }
        if (z1) { vb0 = vb1 = vb2 = f32x4{0.f, 0.f, 0.f, 0.f}; offb = 0.f; }
    }

    // Epilogue: o = cut ? 0 : v*cmul + off_row; NT stores.
    #pragma unroll
    for (int c = 0; c < Cc; ++c) {
        const f32x4 va = (c == 0) ? va0 : (c == 1) ? va1 : va2;
        const f32x4 vb = (c == 0) ? vb0 : (c == 1) ? vb1 : vb2;
        f32x4 oa, ob;
        #pragma unroll
        for (int j = 0; j < 4; ++j) {
            oa[j] = (hcut0 & wcut[j]) ? 0.f : va[j] * cmul + offa;
            ob[j] = (hcut1 & wcut[j]) ? 0.f : vb[j] * cmul + offb;
        }
        store_nt(&out[dst0 + c * CH], oa);
        store_nt(&out[dst0 + c * CH + Wc], ob);
    }
}

extern "C" void kernel_launch(void* const* d_in, const int* in_sizes, int n_in,
                              void* d_out, int out_size, void* d_ws, size_t ws_size,
                              hipStream_t stream) {
    const float* x          = (const float*)d_in[0];
    const float* p          = (const float*)d_in[1];
    const float* flip_u     = (const float*)d_in[2];
    const float* bright_n   = (const float*)d_in[3];
    const float* bright_u   = (const float*)d_in[4];
    const float* contrast_n = (const float*)d_in[5];
    const float* contrast_u = (const float*)d_in[6];
    const int*   trans_h    = (const int*)d_in[7];
    const int*   trans_w    = (const int*)d_in[8];
    const float* trans_u    = (const float*)d_in[9];
    const int*   cut_ox     = (const int*)d_in[10];
    const int*   cut_oy     = (const int*)d_in[11];
    const float* cut_u      = (const float*)d_in[12];
    float*       out        = (float*)d_out;

    dim3 grid(Bc * Hc / 8);    // 2048 blocks: (b, h-octet); wave = 2 rows x 3 ch
    dim3 block(256);
    diffaug_kernel<<<grid, block, 0, stream>>>(
        x, p, flip_u, bright_n, bright_u, contrast_n, contrast_u,
        trans_h, trans_w, trans_u, cut_ox, cut_oy, cut_u, out);
}